// Round 5
// baseline (465.759 us; speedup 1.0000x reference)
//
#include <hip/hip_runtime.h>
#include <hip/hip_bf16.h>
#include <math.h>

#define EMB_DIM 4096
#define INNER   1024
#define VOCAB   32000
#define NPRED   3
#define SEQ     512
#define TOKENS  1024   // B*N = 2*512

typedef __attribute__((ext_vector_type(8))) short bf16x8;
typedef __attribute__((ext_vector_type(4))) float f32x4;

__device__ inline void gload_lds16(const void* g, void* l) {
  __builtin_amdgcn_global_load_lds(
      (const __attribute__((address_space(1))) void*)g,
      (__attribute__((address_space(3))) void*)l, 16, 0, 0);
}

__device__ inline unsigned short f2bf(float f) {
  unsigned u = __float_as_uint(f);
  u += 0x7fffu + ((u >> 16) & 1u);
  return (unsigned short)(u >> 16);
}

// ---------------- f32 -> bf16 convert, x4 vectorized ----------------
__global__ void cvt_kernel(const float4* __restrict__ in, ushort4* __restrict__ out, int n4) {
  int stride = gridDim.x * blockDim.x;
  for (int i = blockIdx.x * blockDim.x + threadIdx.x; i < n4; i += stride) {
    float4 v = in[i];
    ushort4 o;
    o.x = f2bf(v.x); o.y = f2bf(v.y); o.z = f2bf(v.z); o.w = f2bf(v.w);
    out[i] = o;
  }
}

// ---------------- merged: 128x64-tile proj GEMM (blocks 0..127) + head cvt --
// GEMM: C[1024][1024] = A[1024][K](bf16) * Bw[1024][K]^T(bf16).
// 128 GEMM blocks (halve exposed proj0 time); blocks 128..1023 convert head_w.
__global__ __launch_bounds__(256) void proj_cvt(const __hip_bfloat16* __restrict__ A,
                                                const __hip_bfloat16* __restrict__ Bw,
                                                float* __restrict__ C, int K,
                                                const float4* __restrict__ cvsrc,
                                                ushort4* __restrict__ cvdst, int n4) {
  if (blockIdx.x >= 128) {
    for (int i = (blockIdx.x - 128) * 256 + threadIdx.x; i < n4; i += 896 * 256) {
      float4 v = cvsrc[i];
      ushort4 o;
      o.x = f2bf(v.x); o.y = f2bf(v.y); o.z = f2bf(v.z); o.w = f2bf(v.w);
      cvdst[i] = o;
    }
    return;
  }
  __shared__ char smem[12288];
  char* As = smem;           // [128][32] bf16 = 8 KB
  char* Bs = smem + 8192;    // [64][32]  bf16 = 4 KB

  const int tid  = threadIdx.x;
  const int lane = tid & 63;
  const int wave = tid >> 6;
  const int wm = wave >> 1, wn = wave & 1;

  const int bm = (blockIdx.x >> 4) * 128;   // 8 m-tiles
  const int bn = (blockIdx.x & 15) * 64;    // 16 n-tiles
  const int N = 1024;

  const char* Ag = (const char*)(A  + (size_t)(bm + (tid >> 2)) * K + (tid & 3) * 8);
  const char* Bg = (const char*)(Bw + (size_t)(bn + (tid >> 2)) * K + (tid & 3) * 8);
  const size_t rowskipA = (size_t)64 * K * 2;

  f32x4 acc[4][2] = {};

  const int fa = (wm * 64 + (lane & 15)) * 64 + (lane >> 4) * 16;
  const int fb = (wn * 32 + (lane & 15)) * 64 + (lane >> 4) * 16;

  for (int k0 = 0; k0 < K; k0 += 32) {
    gload_lds16(Ag,            As + tid * 16);
    gload_lds16(Ag + rowskipA, As + 4096 + tid * 16);
    gload_lds16(Bg,            Bs + tid * 16);   // 64 rows = 256 chunks = 1/thread
    Ag += 64; Bg += 64;
    __syncthreads();

    bf16x8 af[4], bfv[2];
#pragma unroll
    for (int m = 0; m < 4; ++m) af[m]  = *(const bf16x8*)(As + fa + m * 1024);
#pragma unroll
    for (int n = 0; n < 2; ++n) bfv[n] = *(const bf16x8*)(Bs + fb + n * 1024);
#pragma unroll
    for (int m = 0; m < 4; ++m)
#pragma unroll
      for (int n = 0; n < 2; ++n)
        acc[m][n] = __builtin_amdgcn_mfma_f32_16x16x32_bf16(af[m], bfv[n], acc[m][n], 0, 0, 0);
    __syncthreads();
  }

  const int r0 = bm + wm * 64 + (lane >> 4) * 4;
  const int c0 = bn + wn * 32 + (lane & 15);
#pragma unroll
  for (int m = 0; m < 4; ++m)
#pragma unroll
    for (int n = 0; n < 2; ++n) {
      float* Cp = C + (size_t)(r0 + m * 16) * N + (c0 + n * 16);
#pragma unroll
      for (int r = 0; r < 4; ++r)
        Cp[(size_t)r * N] = acc[m][n][r];
    }
}

// ---------------- 128x128 head GEMM: ring-4 fine-phased, 2 blocks/CU --------
// C[M][N] = A[M][K](bf16) * B[N][K]^T(bf16) -> f32. BK=32, 4 waves (2x2),
// per-wave 64x64 = 4x4 frags. LDS 64KB: A ring-4 @0 (4x8KB), B ring-4 @32768.
// Stage tile t+3 during compute of t; vmcnt(8) keeps tiles t+1,t+2 in flight.
__global__ __launch_bounds__(256, 2) void gemm128(const __hip_bfloat16* __restrict__ A,
                                                  const __hip_bfloat16* __restrict__ B,
                                                  float* __restrict__ C,
                                                  int M, int N, int K) {
  __shared__ char smem[65536];
  const int tid  = threadIdx.x;
  const int lane = tid & 63;
  const int wave = tid >> 6;
  const int wm = wave >> 1;   // 0..1
  const int wn = wave & 1;    // 0..1

  // bijective chunked XCD swizzle (m204), m-fastest decode for B-panel L2 reuse
  const int MT = M >> 7;
  const int nwg = gridDim.x;
  const int o = blockIdx.x;
  const int q = nwg >> 3, r = nwg & 7;
  const int xcd = o & 7, idx = o >> 3;
  const int wg = (xcd < r ? xcd * (q + 1) : r * (q + 1) + (xcd - r) * q) + idx;
  const int bm = (wg % MT) * 128;
  const int bn = (wg / MT) * 128;

  f32x4 acc[4][4] = {};

  // frag read offsets (swizzled): row stride 64B, slot(16B) ^= (row>>1)&3
  const int sl   = (lane >> 4) ^ ((lane >> 1) & 3);
  const int aoff = (wm * 64 + (lane & 15)) * 64 + sl * 16;
  const int boff = (wn * 64 + (lane & 15)) * 64 + sl * 16;

  // stage one 128x32 bf16 tile (8KB = 512 chunks of 16B); 256 thr x 2 chunks.
  // linear LDS dest; source slot pre-swizzled (involution of read-side XOR).
#define STAGE_T(PTR, BASEROW, LDSBASE, KT_)                                     \
  {                                                                             \
    _Pragma("unroll")                                                           \
    for (int c = 0; c < 2; ++c) {                                               \
      int chunk = c * 256 + tid;                                                \
      int row = chunk >> 2;                                                     \
      int s = (chunk & 3) ^ ((row >> 1) & 3);                                   \
      gload_lds16(PTR + (size_t)((BASEROW) + row) * K + (KT_) * 32 + s * 8,     \
                  smem + (LDSBASE) + chunk * 16);                               \
    }                                                                           \
  }

  // prologue: stage tiles 0,1,2 into ring slots 0,1,2 (12 loads in flight)
  STAGE_T(A, bm, 0,             0)
  STAGE_T(B, bn, 32768,         0)
  STAGE_T(A, bm, 8192,          1)
  STAGE_T(B, bn, 32768 + 8192,  1)
  STAGE_T(A, bm, 16384,         2)
  STAGE_T(B, bn, 32768 + 16384, 2)

  const int KT = K >> 5;
  for (int t = 0; t < KT; ++t) {
    const int bc = (t & 3) * 8192;         // compute buffer
    const int bs = ((t + 3) & 3) * 8192;   // stage target (read at t-1, now free)
    const char* Ab = smem + bc;
    const char* Bb = smem + 32768 + bc;

    // tile t's 4 loads are the oldest; vmcnt(8) forces them landed while
    // keeping tiles t+1,t+2 (8 loads) in flight across the barrier.
    asm volatile("s_waitcnt vmcnt(8)" ::: "memory");
    __builtin_amdgcn_s_barrier();          // all waves: tile t staged, t-1 reads done

    const int pk = (t + 3 < KT) ? t + 3 : KT - 1;  // tail clamp keeps counts uniform

    // ---- phase 0: A-frags m0..3 + B-frags n0..1; stage A of tile t+3 ----
    bf16x8 af[4], bf01[2];
#pragma unroll
    for (int m = 0; m < 4; ++m) af[m] = *(const bf16x8*)(Ab + aoff + m * 1024);
#pragma unroll
    for (int n = 0; n < 2; ++n) bf01[n] = *(const bf16x8*)(Bb + boff + n * 1024);
    STAGE_T(A, bm, bs, pk)
    asm volatile("s_waitcnt lgkmcnt(0)" ::: "memory");
    __builtin_amdgcn_sched_barrier(0);
    __builtin_amdgcn_s_setprio(1);
#pragma unroll
    for (int m = 0; m < 4; ++m)
#pragma unroll
      for (int n = 0; n < 2; ++n)
        acc[m][n] = __builtin_amdgcn_mfma_f32_16x16x32_bf16(af[m], bf01[n], acc[m][n], 0, 0, 0);
    __builtin_amdgcn_s_setprio(0);

    // ---- phase 1: B-frags n2..3; stage B of tile t+3 ----
    bf16x8 bf23[2];
#pragma unroll
    for (int n = 0; n < 2; ++n) bf23[n] = *(const bf16x8*)(Bb + boff + (n + 2) * 1024);
    STAGE_T(B, bn, 32768 + bs, pk)
    asm volatile("s_waitcnt lgkmcnt(0)" ::: "memory");
    __builtin_amdgcn_sched_barrier(0);
    __builtin_amdgcn_s_setprio(1);
#pragma unroll
    for (int m = 0; m < 4; ++m)
#pragma unroll
      for (int n = 0; n < 2; ++n)
        acc[m][n + 2] = __builtin_amdgcn_mfma_f32_16x16x32_bf16(af[m], bf23[n], acc[m][n + 2], 0, 0, 0);
    __builtin_amdgcn_s_setprio(0);
    __builtin_amdgcn_sched_barrier(0);
  }
  asm volatile("s_waitcnt vmcnt(0)" ::: "memory");  // drain DMA before wave exit

  // epilogue: C/D layout col = lane&15, row = (lane>>4)*4 + rr
  const int r0 = bm + wm * 64 + (lane >> 4) * 4;
  const int c0 = bn + wn * 64 + (lane & 15);
#pragma unroll
  for (int m = 0; m < 4; ++m)
#pragma unroll
    for (int n = 0; n < 4; ++n) {
      float* Cp = C + (size_t)(r0 + m * 16) * N + (c0 + n * 16);
#pragma unroll
      for (int rr = 0; rr < 4; ++rr)
        Cp[(size_t)rr * N] = acc[m][n][rr];
    }
#undef STAGE_T
}

// ---------------- fused: s = ns + alpha*z ; RMS-LN ; exact GELU ; -> bf16 ----
__global__ __launch_bounds__(256) void fuse_ln_gelu(const float* __restrict__ ns,
    const float* __restrict__ emb,
    const int* __restrict__ inds,
    const float* __restrict__ lnw, const float* __restrict__ lnb,
    ushort4* __restrict__ out_bf16,
    int i, float alpha)
{
  const int t = blockIdx.x;
  const int b = t >> 9, n = t & 511;
  const int idx = inds[b * (SEQ + NPRED) + n + i];

  const float4* x = (const float4*)(ns + (size_t)t * INNER);
  const float4* z = (const float4*)(emb + (size_t)idx * INNER);
  const int j = threadIdx.x;

  float4 xv = x[j], zv = z[j];
  float4 v;
  v.x = xv.x + alpha * zv.x;
  v.y = xv.y + alpha * zv.y;
  v.z = xv.z + alpha * zv.z;
  v.w = xv.w + alpha * zv.w;

  float ss = v.x * v.x + v.y * v.y + v.z * v.z + v.w * v.w;
#pragma unroll
  for (int o = 32; o > 0; o >>= 1) ss += __shfl_down(ss, o);
  __shared__ float red[4];
  if ((threadIdx.x & 63) == 0) red[threadIdx.x >> 6] = ss;
  __syncthreads();
  float total = red[0] + red[1] + red[2] + red[3];
  float r = rsqrtf(total * (1.0f / INNER) + 1e-6f);

  float4 wv = ((const float4*)lnw)[j];
  float4 bv = ((const float4*)lnb)[j];
  const float inv_sqrt2 = 0.70710678118654752f;
  ushort4 o;
  float y;
  y = v.x * r * wv.x + bv.x; o.x = f2bf(0.5f * y * (1.0f + erff(y * inv_sqrt2)));
  y = v.y * r * wv.y + bv.y; o.y = f2bf(0.5f * y * (1.0f + erff(y * inv_sqrt2)));
  y = v.z * r * wv.z + bv.z; o.z = f2bf(0.5f * y * (1.0f + erff(y * inv_sqrt2)));
  y = v.w * r * wv.w + bv.w; o.w = f2bf(0.5f * y * (1.0f + erff(y * inv_sqrt2)));

  out_bf16[(size_t)t * (INNER / 4) + j] = o;
}

extern "C" void kernel_launch(void* const* d_in, const int* in_sizes, int n_in,
                              void* d_out, int out_size, void* d_ws, size_t ws_size,
                              hipStream_t stream) {
  const float* state = (const float*)d_in[0];
  const int*   inds  = (const int*)d_in[1];
  const float* emb_w = (const float*)d_in[2];
  const float* proj0 = (const float*)d_in[3];
  const float* projw = (const float*)d_in[4];
  const float* headw = (const float*)d_in[5];
  const float* lnw   = (const float*)d_in[6];
  const float* lnb   = (const float*)d_in[7];
  float* out = (float*)d_out;

  char* ws = (char*)d_ws;
  __hip_bfloat16* stateA = (__hip_bfloat16*)(ws);                    // 1024*4096 bf16
  __hip_bfloat16* stateI = (__hip_bfloat16*)(ws + 8388608);          // 1024*1024 bf16
  float*          nsf    = (float*)        (ws + 10485760);          // 1024*1024 f32
  __hip_bfloat16* p0b    = (__hip_bfloat16*)(ws + 14680064);         // 1024*4096 bf16
  __hip_bfloat16* pwb    = (__hip_bfloat16*)(ws + 23068672);         // 2*1024*1024 bf16
  __hip_bfloat16* hb     = (__hip_bfloat16*)(ws + 27262976);         // 32000*1024 bf16

  double sw = pow(0.5, 1.0 / 6.0);
  float alpha = (float)(sqrt((1.0 - sw * sw) * (INNER / 2.0)) / sw);

  auto cvt = [&](const float* src, __hip_bfloat16* dst, size_t n) {
    int n4 = (int)(n / 4);
    int blocks = (n4 + 255) / 256;
    if (blocks > 2048) blocks = 2048;
    cvt_kernel<<<dim3(blocks), dim3(256), 0, stream>>>((const float4*)src, (ushort4*)dst, n4);
  };

  // pre-convert state + proj weights (head weights convert inside proj_cvt)
  cvt(state, stateA, (size_t)TOKENS * EMB_DIM);
  cvt(proj0, p0b, (size_t)INNER * EMB_DIM);
  cvt(projw, pwb, (size_t)2 * INNER * INNER);

  for (int i = 0; i < NPRED; ++i) {
    const __hip_bfloat16* Ab = (i == 0) ? stateA : stateI;
    const __hip_bfloat16* Bb = (i == 0) ? p0b : pwb + (size_t)(i - 1) * INNER * INNER;
    int K = (i == 0) ? EMB_DIM : INNER;

    proj_cvt<<<dim3(1024), dim3(256), 0, stream>>>(Ab, Bb, nsf, K,
        (const float4*)(headw + (size_t)i * VOCAB * INNER), (ushort4*)hb,
        (int)((size_t)VOCAB * INNER / 4));

    fuse_ln_gelu<<<dim3(TOKENS), dim3(256), 0, stream>>>(nsf,
        emb_w + (size_t)i * VOCAB * INNER, inds,
        lnw + i * INNER, lnb + i * INNER, (ushort4*)stateI, i, alpha);

    gemm128<<<dim3(2000), dim3(256), 0, stream>>>(stateI, hb,
        out + (size_t)i * TOKENS * VOCAB, TOKENS, VOCAB, INNER);
  }
}

// Round 6
// 445.780 us; speedup vs baseline: 1.0448x; 1.0448x over previous
//
#include <hip/hip_runtime.h>
#include <hip/hip_bf16.h>
#include <math.h>

#define EMB_DIM 4096
#define INNER   1024
#define VOCAB   32000
#define NPRED   3
#define SEQ     512
#define TOKENS  1024   // B*N = 2*512

typedef __attribute__((ext_vector_type(8))) short bf16x8;
typedef __attribute__((ext_vector_type(4))) float f32x4;

__device__ inline void gload_lds16(const void* g, void* l) {
  __builtin_amdgcn_global_load_lds(
      (const __attribute__((address_space(1))) void*)g,
      (__attribute__((address_space(3))) void*)l, 16, 0, 0);
}

__device__ inline unsigned short f2bf(float f) {
  unsigned u = __float_as_uint(f);
  u += 0x7fffu + ((u >> 16) & 1u);
  return (unsigned short)(u >> 16);
}

// ---------------- f32 -> bf16 convert, x4 vectorized ----------------
__global__ void cvt_kernel(const float4* __restrict__ in, ushort4* __restrict__ out, int n4) {
  int stride = gridDim.x * blockDim.x;
  for (int i = blockIdx.x * blockDim.x + threadIdx.x; i < n4; i += stride) {
    float4 v = in[i];
    ushort4 o;
    o.x = f2bf(v.x); o.y = f2bf(v.y); o.z = f2bf(v.z); o.w = f2bf(v.w);
    out[i] = o;
  }
}

// ---------------- merged: 128x128 proj GEMM (blocks 0..63) + head cvt (64..1023)
__global__ __launch_bounds__(256) void proj_cvt(const __hip_bfloat16* __restrict__ A,
                                                const __hip_bfloat16* __restrict__ Bw,
                                                float* __restrict__ C, int K,
                                                const float4* __restrict__ cvsrc,
                                                ushort4* __restrict__ cvdst, int n4) {
  if (blockIdx.x >= 64) {
    for (int i = (blockIdx.x - 64) * 256 + threadIdx.x; i < n4; i += 960 * 256) {
      float4 v = cvsrc[i];
      ushort4 o;
      o.x = f2bf(v.x); o.y = f2bf(v.y); o.z = f2bf(v.z); o.w = f2bf(v.w);
      cvdst[i] = o;
    }
    return;
  }
  __shared__ char smem[16384];
  char* As = smem;          // [128][32] bf16
  char* Bs = smem + 8192;   // [128][32] bf16

  const int tid  = threadIdx.x;
  const int lane = tid & 63;
  const int wave = tid >> 6;
  const int wm = wave >> 1, wn = wave & 1;

  const int bm = (blockIdx.x >> 3) * 128;
  const int bn = (blockIdx.x & 7) * 128;
  const int N = 1024;

  const char* Ag = (const char*)(A  + (size_t)(bm + (tid >> 2)) * K + (tid & 3) * 8);
  const char* Bg = (const char*)(Bw + (size_t)(bn + (tid >> 2)) * K + (tid & 3) * 8);
  const size_t rowskip = (size_t)64 * K * 2;

  f32x4 acc[4][4] = {};

  const int fa = (wm * 64 + (lane & 15)) * 64 + (lane >> 4) * 16;
  const int fb = (wn * 64 + (lane & 15)) * 64 + (lane >> 4) * 16;

  for (int k0 = 0; k0 < K; k0 += 32) {
    gload_lds16(Ag,           As + tid * 16);
    gload_lds16(Ag + rowskip, As + 4096 + tid * 16);
    gload_lds16(Bg,           Bs + tid * 16);
    gload_lds16(Bg + rowskip, Bs + 4096 + tid * 16);
    Ag += 64; Bg += 64;
    __syncthreads();

    bf16x8 af[4], bfv[4];
#pragma unroll
    for (int m = 0; m < 4; ++m) af[m]  = *(const bf16x8*)(As + fa + m * 1024);
#pragma unroll
    for (int n = 0; n < 4; ++n) bfv[n] = *(const bf16x8*)(Bs + fb + n * 1024);
#pragma unroll
    for (int m = 0; m < 4; ++m)
#pragma unroll
      for (int n = 0; n < 4; ++n)
        acc[m][n] = __builtin_amdgcn_mfma_f32_16x16x32_bf16(af[m], bfv[n], acc[m][n], 0, 0, 0);
    __syncthreads();
  }

  const int r0 = bm + wm * 64 + (lane >> 4) * 4;
  const int c0 = bn + wn * 64 + (lane & 15);
#pragma unroll
  for (int m = 0; m < 4; ++m)
#pragma unroll
    for (int n = 0; n < 4; ++n) {
      float* Cp = C + (size_t)(r0 + m * 16) * N + (c0 + n * 16);
#pragma unroll
      for (int r = 0; r < 4; ++r)
        Cp[(size_t)r * N] = acc[m][n][r];
    }
}

// ---------------- 256x256 head GEMM: 8-phase (4/K-tile), counted vmcnt(4) ---
// C[M][N] = A[M][K](bf16) * B[N][K]^T(bf16) -> f32. BK=64, 8 waves (2Mx4N),
// per-wave 128x64 = 8x4 frags. LDS 128KB = 2 buffers x 4 units of 16KB:
//   buf p: [SA-k0 @0][SA-k1 @16384][SB-k0 @32768][SB-k1 @49152]
// Per K-tile: 4 phases {ds_read 8|4, stage 1 unit, barrier, lgkm0, 16 MFMA,
// barrier}. Stage order SAk0,SBk0,SAk1,SBk1 of tile t+1 during tile t's
// phases 1-4; vmcnt(4) at phases 2 & 4 forces exactly the units the next
// phase reads while keeping 4 loads in flight. Reads of a region always
// follow a barrier preceded by every wave's forcing vmcnt.
__global__ __launch_bounds__(512, 2) void gemm256_8p(const __hip_bfloat16* __restrict__ A,
                                                     const __hip_bfloat16* __restrict__ B,
                                                     float* __restrict__ C,
                                                     int M, int N, int K) {
  __shared__ char smem[131072];
  const int tid  = threadIdx.x;
  const int lane = tid & 63;
  const int wave = tid >> 6;
  const int wm = wave >> 2;   // 0..1
  const int wn = wave & 3;    // 0..3

  // bijective chunked XCD swizzle (m204), m-fastest decode for B-panel L2 reuse
  const int MT = M >> 8;
  const int nwg = gridDim.x;
  const int o = blockIdx.x;
  const int q = nwg >> 3, r = nwg & 7;
  const int xcd = o & 7, idx = o >> 3;
  const int wg = (xcd < r ? xcd * (q + 1) : r * (q + 1) + (xcd - r) * q) + idx;
  const int bm = (wg % MT) * 256;
  const int bn = (wg / MT) * 256;

  f32x4 acc[8][4] = {};

  // frag read offsets within a 16KB unit: row stride 64B, slot ^= (row>>1)&3
  const int sl   = (lane >> 4) ^ ((lane >> 1) & 3);
  const int aoff = (wm * 128 + (lane & 15)) * 64 + sl * 16;
  const int boff = (wn * 64  + (lane & 15)) * 64 + sl * 16;

  // stage one 16KB unit: 256 rows x 32 bf16 (one k-half). 1024 chunks of 16B,
  // 512 thr x 2. Linear LDS dest; source slot pre-swizzled (read-XOR involution).
#define STAGE_U(PTR, BASEROW, LDSBASE, T_, KQ_)                                 \
  {                                                                             \
    _Pragma("unroll")                                                           \
    for (int c = 0; c < 2; ++c) {                                               \
      int chunk = c * 512 + tid;                                                \
      int row = chunk >> 2;                                                     \
      int s = (chunk & 3) ^ ((row >> 1) & 3);                                   \
      gload_lds16(PTR + (size_t)((BASEROW) + row) * K + (T_) * 64 + (KQ_) * 32 + s * 8, \
                  smem + (LDSBASE) + chunk * 16);                               \
    }                                                                           \
  }

  // prologue: tile 0's four units into buffer 0 (order: SAk0, SBk0, SAk1, SBk1)
  STAGE_U(A, bm, 0,             0, 0)
  STAGE_U(B, bn, 32768,         0, 0)
  STAGE_U(A, bm, 16384,         0, 1)
  STAGE_U(B, bn, 49152,         0, 1)
  asm volatile("s_waitcnt vmcnt(4)" ::: "memory");   // SAk0+SBk0 landed; k1 flying
  __builtin_amdgcn_s_barrier();

  const int KT = K >> 6;   // BK=64
  for (int t = 0; t < KT; ++t) {
    const int lp = (t & 1) << 16;          // compute buffer
    const int lo = ((t + 1) & 1) << 16;    // stage buffer (tile t+1)
    const int pt = (t + 1 < KT) ? t + 1 : KT - 1;  // tail clamp: uniform counts
    bf16x8 af[4], bfv[4];

    // ---- phase 1: k0, m-low (acc[0..3]); stage SA(t+1,k0) ----
#pragma unroll
    for (int m = 0; m < 4; ++m) af[m]  = *(const bf16x8*)(smem + lp + aoff + m * 1024);
#pragma unroll
    for (int n = 0; n < 4; ++n) bfv[n] = *(const bf16x8*)(smem + lp + 32768 + boff + n * 1024);
    STAGE_U(A, bm, lo, pt, 0)
    __builtin_amdgcn_s_barrier();
    asm volatile("s_waitcnt lgkmcnt(0)" ::: "memory");
    __builtin_amdgcn_sched_barrier(0);
    __builtin_amdgcn_s_setprio(1);
#pragma unroll
    for (int m = 0; m < 4; ++m)
#pragma unroll
      for (int n = 0; n < 4; ++n)
        acc[m][n] = __builtin_amdgcn_mfma_f32_16x16x32_bf16(af[m], bfv[n], acc[m][n], 0, 0, 0);
    __builtin_amdgcn_s_setprio(0);
    __builtin_amdgcn_s_barrier();

    // ---- phase 2: k0, m-high (acc[4..7]); stage SB(t+1,k0); vmcnt(4) ----
#pragma unroll
    for (int m = 0; m < 4; ++m) af[m] = *(const bf16x8*)(smem + lp + 4096 + aoff + m * 1024);
    STAGE_U(B, bn, lo + 32768, pt, 0)
    asm volatile("s_waitcnt vmcnt(4)" ::: "memory");  // forces SA/SB(t,k1) for phase 3
    __builtin_amdgcn_s_barrier();
    asm volatile("s_waitcnt lgkmcnt(0)" ::: "memory");
    __builtin_amdgcn_sched_barrier(0);
    __builtin_amdgcn_s_setprio(1);
#pragma unroll
    for (int m = 0; m < 4; ++m)
#pragma unroll
      for (int n = 0; n < 4; ++n)
        acc[m + 4][n] = __builtin_amdgcn_mfma_f32_16x16x32_bf16(af[m], bfv[n], acc[m + 4][n], 0, 0, 0);
    __builtin_amdgcn_s_setprio(0);
    __builtin_amdgcn_s_barrier();

    // ---- phase 3: k1, m-low; stage SA(t+1,k1) ----
#pragma unroll
    for (int m = 0; m < 4; ++m) af[m]  = *(const bf16x8*)(smem + lp + 16384 + aoff + m * 1024);
#pragma unroll
    for (int n = 0; n < 4; ++n) bfv[n] = *(const bf16x8*)(smem + lp + 49152 + boff + n * 1024);
    STAGE_U(A, bm, lo + 16384, pt, 1)
    __builtin_amdgcn_s_barrier();
    asm volatile("s_waitcnt lgkmcnt(0)" ::: "memory");
    __builtin_amdgcn_sched_barrier(0);
    __builtin_amdgcn_s_setprio(1);
#pragma unroll
    for (int m = 0; m < 4; ++m)
#pragma unroll
      for (int n = 0; n < 4; ++n)
        acc[m][n] = __builtin_amdgcn_mfma_f32_16x16x32_bf16(af[m], bfv[n], acc[m][n], 0, 0, 0);
    __builtin_amdgcn_s_setprio(0);
    __builtin_amdgcn_s_barrier();

    // ---- phase 4: k1, m-high; stage SB(t+1,k1); vmcnt(4) ----
#pragma unroll
    for (int m = 0; m < 4; ++m) af[m] = *(const bf16x8*)(smem + lp + 16384 + 4096 + aoff + m * 1024);
    STAGE_U(B, bn, lo + 49152, pt, 1)
    asm volatile("s_waitcnt vmcnt(4)" ::: "memory");  // forces SA/SB(t+1,k0) for next phase 1
    __builtin_amdgcn_s_barrier();
    asm volatile("s_waitcnt lgkmcnt(0)" ::: "memory");
    __builtin_amdgcn_sched_barrier(0);
    __builtin_amdgcn_s_setprio(1);
#pragma unroll
    for (int m = 0; m < 4; ++m)
#pragma unroll
      for (int n = 0; n < 4; ++n)
        acc[m + 4][n] = __builtin_amdgcn_mfma_f32_16x16x32_bf16(af[m], bfv[n], acc[m + 4][n], 0, 0, 0);
    __builtin_amdgcn_s_setprio(0);
    __builtin_amdgcn_s_barrier();
  }
  asm volatile("s_waitcnt vmcnt(0)" ::: "memory");  // drain DMA before wave exit

  // epilogue: C/D layout col = lane&15, row = (lane>>4)*4 + rr
  const int r0 = bm + wm * 128 + (lane >> 4) * 4;
  const int c0 = bn + wn * 64 + (lane & 15);
#pragma unroll
  for (int m = 0; m < 8; ++m)
#pragma unroll
    for (int n = 0; n < 4; ++n) {
      float* Cp = C + (size_t)(r0 + m * 16) * N + (c0 + n * 16);
#pragma unroll
      for (int rr = 0; rr < 4; ++rr)
        Cp[(size_t)rr * N] = acc[m][n][rr];
    }
#undef STAGE_U
}

// ---------------- fused: s = ns + alpha*z ; RMS-LN ; exact GELU ; -> bf16 ----
__global__ __launch_bounds__(256) void fuse_ln_gelu(const float* __restrict__ ns,
    const float* __restrict__ emb,
    const int* __restrict__ inds,
    const float* __restrict__ lnw, const float* __restrict__ lnb,
    ushort4* __restrict__ out_bf16,
    int i, float alpha)
{
  const int t = blockIdx.x;
  const int b = t >> 9, n = t & 511;
  const int idx = inds[b * (SEQ + NPRED) + n + i];

  const float4* x = (const float4*)(ns + (size_t)t * INNER);
  const float4* z = (const float4*)(emb + (size_t)idx * INNER);
  const int j = threadIdx.x;

  float4 xv = x[j], zv = z[j];
  float4 v;
  v.x = xv.x + alpha * zv.x;
  v.y = xv.y + alpha * zv.y;
  v.z = xv.z + alpha * zv.z;
  v.w = xv.w + alpha * zv.w;

  float ss = v.x * v.x + v.y * v.y + v.z * v.z + v.w * v.w;
#pragma unroll
  for (int o = 32; o > 0; o >>= 1) ss += __shfl_down(ss, o);
  __shared__ float red[4];
  if ((threadIdx.x & 63) == 0) red[threadIdx.x >> 6] = ss;
  __syncthreads();
  float total = red[0] + red[1] + red[2] + red[3];
  float r = rsqrtf(total * (1.0f / INNER) + 1e-6f);

  float4 wv = ((const float4*)lnw)[j];
  float4 bv = ((const float4*)lnb)[j];
  const float inv_sqrt2 = 0.70710678118654752f;
  ushort4 o;
  float y;
  y = v.x * r * wv.x + bv.x; o.x = f2bf(0.5f * y * (1.0f + erff(y * inv_sqrt2)));
  y = v.y * r * wv.y + bv.y; o.y = f2bf(0.5f * y * (1.0f + erff(y * inv_sqrt2)));
  y = v.z * r * wv.z + bv.z; o.z = f2bf(0.5f * y * (1.0f + erff(y * inv_sqrt2)));
  y = v.w * r * wv.w + bv.w; o.w = f2bf(0.5f * y * (1.0f + erff(y * inv_sqrt2)));

  out_bf16[(size_t)t * (INNER / 4) + j] = o;
}

extern "C" void kernel_launch(void* const* d_in, const int* in_sizes, int n_in,
                              void* d_out, int out_size, void* d_ws, size_t ws_size,
                              hipStream_t stream) {
  const float* state = (const float*)d_in[0];
  const int*   inds  = (const int*)d_in[1];
  const float* emb_w = (const float*)d_in[2];
  const float* proj0 = (const float*)d_in[3];
  const float* projw = (const float*)d_in[4];
  const float* headw = (const float*)d_in[5];
  const float* lnw   = (const float*)d_in[6];
  const float* lnb   = (const float*)d_in[7];
  float* out = (float*)d_out;

  char* ws = (char*)d_ws;
  __hip_bfloat16* stateA = (__hip_bfloat16*)(ws);                    // 1024*4096 bf16
  __hip_bfloat16* stateI = (__hip_bfloat16*)(ws + 8388608);          // 1024*1024 bf16
  float*          nsf    = (float*)        (ws + 10485760);          // 1024*1024 f32
  __hip_bfloat16* p0b    = (__hip_bfloat16*)(ws + 14680064);         // 1024*4096 bf16
  __hip_bfloat16* pwb    = (__hip_bfloat16*)(ws + 23068672);         // 2*1024*1024 bf16
  __hip_bfloat16* hb     = (__hip_bfloat16*)(ws + 27262976);         // 32000*1024 bf16

  double sw = pow(0.5, 1.0 / 6.0);
  float alpha = (float)(sqrt((1.0 - sw * sw) * (INNER / 2.0)) / sw);

  auto cvt = [&](const float* src, __hip_bfloat16* dst, size_t n) {
    int n4 = (int)(n / 4);
    int blocks = (n4 + 255) / 256;
    if (blocks > 2048) blocks = 2048;
    cvt_kernel<<<dim3(blocks), dim3(256), 0, stream>>>((const float4*)src, (ushort4*)dst, n4);
  };

  // pre-convert state + proj weights (head weights convert inside proj_cvt)
  cvt(state, stateA, (size_t)TOKENS * EMB_DIM);
  cvt(proj0, p0b, (size_t)INNER * EMB_DIM);
  cvt(projw, pwb, (size_t)2 * INNER * INNER);

  for (int i = 0; i < NPRED; ++i) {
    const __hip_bfloat16* Ab = (i == 0) ? stateA : stateI;
    const __hip_bfloat16* Bb = (i == 0) ? p0b : pwb + (size_t)(i - 1) * INNER * INNER;
    int K = (i == 0) ? EMB_DIM : INNER;

    proj_cvt<<<dim3(1024), dim3(256), 0, stream>>>(Ab, Bb, nsf, K,
        (const float4*)(headw + (size_t)i * VOCAB * INNER), (ushort4*)hb,
        (int)((size_t)VOCAB * INNER / 4));

    fuse_ln_gelu<<<dim3(TOKENS), dim3(256), 0, stream>>>(nsf,
        emb_w + (size_t)i * VOCAB * INNER, inds,
        lnw + i * INNER, lnb + i * INNER, (ushort4*)stateI, i, alpha);

    gemm256_8p<<<dim3(500), dim3(512), 0, stream>>>(stateI, hb,
        out + (size_t)i * TOKENS * VOCAB, TOKENS, VOCAB, INNER);
  }
}

// Round 7
// 441.533 us; speedup vs baseline: 1.0549x; 1.0096x over previous
//
#include <hip/hip_runtime.h>
#include <hip/hip_bf16.h>
#include <math.h>

#define EMB_DIM 4096
#define INNER   1024
#define VOCAB   32000
#define NPRED   3
#define SEQ     512
#define TOKENS  1024   // B*N = 2*512

typedef __attribute__((ext_vector_type(8))) short bf16x8;
typedef __attribute__((ext_vector_type(4))) float f32x4;

__device__ inline void gload_lds16(const void* g, void* l) {
  __builtin_amdgcn_global_load_lds(
      (const __attribute__((address_space(1))) void*)g,
      (__attribute__((address_space(3))) void*)l, 16, 0, 0);
}

__device__ inline unsigned short f2bf(float f) {
  unsigned u = __float_as_uint(f);
  u += 0x7fffu + ((u >> 16) & 1u);
  return (unsigned short)(u >> 16);
}

// ---------------- f32 -> bf16 convert, x4 vectorized ----------------
__global__ void cvt_kernel(const float4* __restrict__ in, ushort4* __restrict__ out, int n4) {
  int stride = gridDim.x * blockDim.x;
  for (int i = blockIdx.x * blockDim.x + threadIdx.x; i < n4; i += stride) {
    float4 v = in[i];
    ushort4 o;
    o.x = f2bf(v.x); o.y = f2bf(v.y); o.z = f2bf(v.z); o.w = f2bf(v.w);
    out[i] = o;
  }
}

// ---------------- merged: 128x128 proj GEMM (blocks 0..63) + head cvt (64..1023)
// Used once for step 0 (K=4096) while converting head_w[0].
__global__ __launch_bounds__(256) void proj_cvt(const __hip_bfloat16* __restrict__ A,
                                                const __hip_bfloat16* __restrict__ Bw,
                                                float* __restrict__ C, int K,
                                                const float4* __restrict__ cvsrc,
                                                ushort4* __restrict__ cvdst, int n4) {
  if (blockIdx.x >= 64) {
    for (int i = (blockIdx.x - 64) * 256 + threadIdx.x; i < n4; i += 960 * 256) {
      float4 v = cvsrc[i];
      ushort4 o;
      o.x = f2bf(v.x); o.y = f2bf(v.y); o.z = f2bf(v.z); o.w = f2bf(v.w);
      cvdst[i] = o;
    }
    return;
  }
  __shared__ char smem[16384];
  char* As = smem;          // [128][32] bf16
  char* Bs = smem + 8192;   // [128][32] bf16

  const int tid  = threadIdx.x;
  const int lane = tid & 63;
  const int wave = tid >> 6;
  const int wm = wave >> 1, wn = wave & 1;

  const int bm = (blockIdx.x >> 3) * 128;
  const int bn = (blockIdx.x & 7) * 128;
  const int N = 1024;

  const char* Ag = (const char*)(A  + (size_t)(bm + (tid >> 2)) * K + (tid & 3) * 8);
  const char* Bg = (const char*)(Bw + (size_t)(bn + (tid >> 2)) * K + (tid & 3) * 8);
  const size_t rowskip = (size_t)64 * K * 2;

  f32x4 acc[4][4] = {};

  const int fa = (wm * 64 + (lane & 15)) * 64 + (lane >> 4) * 16;
  const int fb = (wn * 64 + (lane & 15)) * 64 + (lane >> 4) * 16;

  for (int k0 = 0; k0 < K; k0 += 32) {
    gload_lds16(Ag,           As + tid * 16);
    gload_lds16(Ag + rowskip, As + 4096 + tid * 16);
    gload_lds16(Bg,           Bs + tid * 16);
    gload_lds16(Bg + rowskip, Bs + 4096 + tid * 16);
    Ag += 64; Bg += 64;
    __syncthreads();

    bf16x8 af[4], bfv[4];
#pragma unroll
    for (int m = 0; m < 4; ++m) af[m]  = *(const bf16x8*)(As + fa + m * 1024);
#pragma unroll
    for (int n = 0; n < 4; ++n) bfv[n] = *(const bf16x8*)(Bs + fb + n * 1024);
#pragma unroll
    for (int m = 0; m < 4; ++m)
#pragma unroll
      for (int n = 0; n < 4; ++n)
        acc[m][n] = __builtin_amdgcn_mfma_f32_16x16x32_bf16(af[m], bfv[n], acc[m][n], 0, 0, 0);
    __syncthreads();
  }

  const int r0 = bm + wm * 64 + (lane >> 4) * 4;
  const int c0 = bn + wn * 64 + (lane & 15);
#pragma unroll
  for (int m = 0; m < 4; ++m)
#pragma unroll
    for (int n = 0; n < 4; ++n) {
      float* Cp = C + (size_t)(r0 + m * 16) * N + (c0 + n * 16);
#pragma unroll
      for (int r = 0; r < 4; ++r)
        Cp[(size_t)r * N] = acc[m][n][r];
    }
}

// ---------------- mega: head GEMM (0..499) + next proj GEMM (500..563) ------
//                      + next head_w cvt (564..1023)
// Head: C[1024][32000] = A[1024][1024](bf16) * B[32000][1024]^T(bf16) -> f32.
// Ring-4 fine-phased 256x256 (round-4 verified). Proj: 128x128 8-wave m97
// structure, K=INNER. Cvt: grid-stride f32->bf16. All data-independent.
__global__ __launch_bounds__(512, 2) void mega(const __hip_bfloat16* __restrict__ A,
                                               const __hip_bfloat16* __restrict__ B,
                                               float* __restrict__ C,
                                               const __hip_bfloat16* __restrict__ Pw,
                                               float* __restrict__ nsf,
                                               const float4* __restrict__ cvsrc,
                                               ushort4* __restrict__ cvdst, int n4) {
  __shared__ char smem[131072];
  const int tid  = threadIdx.x;
  const int lane = tid & 63;
  const int wave = tid >> 6;

  if (blockIdx.x >= 564) {
    // ---- head_w(i+1) f32 -> bf16, 460 blocks x 512 thr ----
    for (int i = (blockIdx.x - 564) * 512 + tid; i < n4; i += 460 * 512) {
      float4 v = cvsrc[i];
      ushort4 o;
      o.x = f2bf(v.x); o.y = f2bf(v.y); o.z = f2bf(v.z); o.w = f2bf(v.w);
      cvdst[i] = o;
    }
    return;
  }

  if (blockIdx.x >= 500) {
    // ---- proj(i+1): 128x128 tile, 8 waves (2Mx4N), per-wave 64x32, K=INNER --
    char* As = smem;          // [128][32] bf16 = 8 KB
    char* Bs = smem + 8192;   // [128][32] bf16 = 8 KB
    const int p = blockIdx.x - 500;
    const int bm = (p >> 3) * 128;
    const int bn = (p & 7) * 128;
    const int wm = wave >> 2, wn = wave & 3;

    const char* Ag = (const char*)(A  + (size_t)(bm + (tid >> 2)) * INNER + (tid & 3) * 8);
    const char* Bg = (const char*)(Pw + (size_t)(bn + (tid >> 2)) * INNER + (tid & 3) * 8);

    f32x4 acc[4][2] = {};
    const int fa = (wm * 64 + (lane & 15)) * 64 + (lane >> 4) * 16;
    const int fb = (wn * 32 + (lane & 15)) * 64 + (lane >> 4) * 16;

    for (int k0 = 0; k0 < INNER; k0 += 32) {
      gload_lds16(Ag, As + tid * 16);
      gload_lds16(Bg, Bs + tid * 16);
      Ag += 64; Bg += 64;
      __syncthreads();
      bf16x8 af[4], bfv[2];
#pragma unroll
      for (int m = 0; m < 4; ++m) af[m]  = *(const bf16x8*)(As + fa + m * 1024);
#pragma unroll
      for (int n = 0; n < 2; ++n) bfv[n] = *(const bf16x8*)(Bs + fb + n * 1024);
#pragma unroll
      for (int m = 0; m < 4; ++m)
#pragma unroll
        for (int n = 0; n < 2; ++n)
          acc[m][n] = __builtin_amdgcn_mfma_f32_16x16x32_bf16(af[m], bfv[n], acc[m][n], 0, 0, 0);
      __syncthreads();
    }
    const int r0 = bm + wm * 64 + (lane >> 4) * 4;
    const int c0 = bn + wn * 32 + (lane & 15);
#pragma unroll
    for (int m = 0; m < 4; ++m)
#pragma unroll
      for (int n = 0; n < 2; ++n) {
        float* Cp = nsf + (size_t)(r0 + m * 16) * INNER + (c0 + n * 16);
#pragma unroll
        for (int r = 0; r < 4; ++r)
          Cp[(size_t)r * INNER] = acc[m][n][r];
      }
    return;
  }

  // ---- head GEMM: ring-4 fine-phased 256x256 (round-4 verified) ----
  const int M = TOKENS, N = VOCAB, K = INNER;
  const int wm = wave >> 2;   // 0..1
  const int wn = wave & 3;    // 0..3

  // bijective chunked XCD swizzle over the 500 head blocks (q=62, r=4)
  const int MT = M >> 8;      // 4
  const int o = blockIdx.x;
  const int q = 500 >> 3, r = 500 & 7;
  const int xcd = o & 7, idx = o >> 3;
  const int wg = (xcd < r ? xcd * (q + 1) : r * (q + 1) + (xcd - r) * q) + idx;
  const int bm = (wg % MT) * 256;
  const int bn = (wg / MT) * 256;

  f32x4 acc[8][4] = {};

  const int sl   = (lane >> 4) ^ ((lane >> 1) & 3);
  const int aoff = (wm * 128 + (lane & 15)) * 64 + sl * 16;
  const int boff = (wn * 64  + (lane & 15)) * 64 + sl * 16;

#define STAGE_T(PTR, BASEROW, LDSBASE, KT_)                                     \
  {                                                                             \
    _Pragma("unroll")                                                           \
    for (int c = 0; c < 2; ++c) {                                               \
      int chunk = c * 512 + tid;                                                \
      int row = chunk >> 2;                                                     \
      int s = (chunk & 3) ^ ((row >> 1) & 3);                                   \
      gload_lds16(PTR + (size_t)((BASEROW) + row) * K + (KT_) * 32 + s * 8,     \
                  smem + (LDSBASE) + chunk * 16);                               \
    }                                                                           \
  }

  STAGE_T(A, bm, 0,             0)
  STAGE_T(B, bn, 65536,         0)
  STAGE_T(A, bm, 16384,         1)
  STAGE_T(B, bn, 65536 + 16384, 1)
  STAGE_T(A, bm, 32768,         2)
  STAGE_T(B, bn, 65536 + 32768, 2)

  const int KT = K >> 5;
  for (int t = 0; t < KT; ++t) {
    const int bc = (t & 3) * 16384;        // compute buffer
    const int bs = ((t + 3) & 3) * 16384;  // stage target (read at t-1, now free)
    const char* Ab = smem + bc;
    const char* Bb = smem + 65536 + bc;

    asm volatile("s_waitcnt vmcnt(8)" ::: "memory");  // tile t landed; t+1,t+2 flying
    __builtin_amdgcn_s_barrier();

    const int pk = (t + 3 < KT) ? t + 3 : KT - 1;

    // phase 0: m-frags 0..3 + all B; stage A of t+3
    bf16x8 af0[4], bfv[4];
#pragma unroll
    for (int m = 0; m < 4; ++m) af0[m] = *(const bf16x8*)(Ab + aoff + m * 1024);
#pragma unroll
    for (int n = 0; n < 4; ++n) bfv[n] = *(const bf16x8*)(Bb + boff + n * 1024);
    STAGE_T(A, bm, bs, pk)
    asm volatile("s_waitcnt lgkmcnt(0)" ::: "memory");
    __builtin_amdgcn_sched_barrier(0);
    __builtin_amdgcn_s_setprio(1);
#pragma unroll
    for (int m = 0; m < 4; ++m)
#pragma unroll
      for (int n = 0; n < 4; ++n)
        acc[m][n] = __builtin_amdgcn_mfma_f32_16x16x32_bf16(af0[m], bfv[n], acc[m][n], 0, 0, 0);
    __builtin_amdgcn_s_setprio(0);

    // phase 1: m-frags 4..7; stage B of t+3
    bf16x8 af1[4];
#pragma unroll
    for (int m = 0; m < 4; ++m) af1[m] = *(const bf16x8*)(Ab + aoff + (m + 4) * 1024);
    STAGE_T(B, bn, 65536 + bs, pk)
    asm volatile("s_waitcnt lgkmcnt(0)" ::: "memory");
    __builtin_amdgcn_sched_barrier(0);
    __builtin_amdgcn_s_setprio(1);
#pragma unroll
    for (int m = 0; m < 4; ++m)
#pragma unroll
      for (int n = 0; n < 4; ++n)
        acc[m + 4][n] = __builtin_amdgcn_mfma_f32_16x16x32_bf16(af1[m], bfv[n], acc[m + 4][n], 0, 0, 0);
    __builtin_amdgcn_s_setprio(0);
    __builtin_amdgcn_sched_barrier(0);
  }
  asm volatile("s_waitcnt vmcnt(0)" ::: "memory");

  const int r0 = bm + wm * 128 + (lane >> 4) * 4;
  const int c0 = bn + wn * 64 + (lane & 15);
#pragma unroll
  for (int m = 0; m < 8; ++m)
#pragma unroll
    for (int n = 0; n < 4; ++n) {
      float* Cp = C + (size_t)(r0 + m * 16) * N + (c0 + n * 16);
#pragma unroll
      for (int rr = 0; rr < 4; ++rr)
        Cp[(size_t)rr * N] = acc[m][n][rr];
    }
#undef STAGE_T
}

// ---------------- fused: s = ns + alpha*z ; RMS-LN ; exact GELU ; -> bf16 ----
__global__ __launch_bounds__(256) void fuse_ln_gelu(const float* __restrict__ ns,
    const float* __restrict__ emb,
    const int* __restrict__ inds,
    const float* __restrict__ lnw, const float* __restrict__ lnb,
    ushort4* __restrict__ out_bf16,
    int i, float alpha)
{
  const int t = blockIdx.x;
  const int b = t >> 9, n = t & 511;
  const int idx = inds[b * (SEQ + NPRED) + n + i];

  const float4* x = (const float4*)(ns + (size_t)t * INNER);
  const float4* z = (const float4*)(emb + (size_t)idx * INNER);
  const int j = threadIdx.x;

  float4 xv = x[j], zv = z[j];
  float4 v;
  v.x = xv.x + alpha * zv.x;
  v.y = xv.y + alpha * zv.y;
  v.z = xv.z + alpha * zv.z;
  v.w = xv.w + alpha * zv.w;

  float ss = v.x * v.x + v.y * v.y + v.z * v.z + v.w * v.w;
#pragma unroll
  for (int o = 32; o > 0; o >>= 1) ss += __shfl_down(ss, o);
  __shared__ float red[4];
  if ((threadIdx.x & 63) == 0) red[threadIdx.x >> 6] = ss;
  __syncthreads();
  float total = red[0] + red[1] + red[2] + red[3];
  float r = rsqrtf(total * (1.0f / INNER) + 1e-6f);

  float4 wv = ((const float4*)lnw)[j];
  float4 bv = ((const float4*)lnb)[j];
  const float inv_sqrt2 = 0.70710678118654752f;
  ushort4 o;
  float y;
  y = v.x * r * wv.x + bv.x; o.x = f2bf(0.5f * y * (1.0f + erff(y * inv_sqrt2)));
  y = v.y * r * wv.y + bv.y; o.y = f2bf(0.5f * y * (1.0f + erff(y * inv_sqrt2)));
  y = v.z * r * wv.z + bv.z; o.z = f2bf(0.5f * y * (1.0f + erff(y * inv_sqrt2)));
  y = v.w * r * wv.w + bv.w; o.w = f2bf(0.5f * y * (1.0f + erff(y * inv_sqrt2)));

  out_bf16[(size_t)t * (INNER / 4) + j] = o;
}

extern "C" void kernel_launch(void* const* d_in, const int* in_sizes, int n_in,
                              void* d_out, int out_size, void* d_ws, size_t ws_size,
                              hipStream_t stream) {
  const float* state = (const float*)d_in[0];
  const int*   inds  = (const int*)d_in[1];
  const float* emb_w = (const float*)d_in[2];
  const float* proj0 = (const float*)d_in[3];
  const float* projw = (const float*)d_in[4];
  const float* headw = (const float*)d_in[5];
  const float* lnw   = (const float*)d_in[6];
  const float* lnb   = (const float*)d_in[7];
  float* out = (float*)d_out;

  char* ws = (char*)d_ws;
  __hip_bfloat16* stateA = (__hip_bfloat16*)(ws);                    // 1024*4096 bf16
  __hip_bfloat16* stateI = (__hip_bfloat16*)(ws + 8388608);          // 1024*1024 bf16
  float*          nsf    = (float*)        (ws + 10485760);          // 1024*1024 f32
  __hip_bfloat16* p0b    = (__hip_bfloat16*)(ws + 14680064);         // 1024*4096 bf16
  __hip_bfloat16* pwb    = (__hip_bfloat16*)(ws + 23068672);         // 2*1024*1024 bf16
  __hip_bfloat16* hb0    = (__hip_bfloat16*)(ws + 27262976);         // 32000*1024 bf16
  __hip_bfloat16* hb1    = (__hip_bfloat16*)(ws + 92798976);         // 32000*1024 bf16
  // total ws use: 158,334,976 bytes

  double sw = pow(0.5, 1.0 / 6.0);
  float alpha = (float)(sqrt((1.0 - sw * sw) * (INNER / 2.0)) / sw);

  auto cvt = [&](const float* src, __hip_bfloat16* dst, size_t n) {
    int n4 = (int)(n / 4);
    int blocks = (n4 + 255) / 256;
    if (blocks > 2048) blocks = 2048;
    cvt_kernel<<<dim3(blocks), dim3(256), 0, stream>>>((const float4*)src, (ushort4*)dst, n4);
  };

  const int hn4 = (int)((size_t)VOCAB * INNER / 4);

  cvt(state, stateA, (size_t)TOKENS * EMB_DIM);
  cvt(proj0, p0b, (size_t)INNER * EMB_DIM);
  cvt(projw, pwb, (size_t)2 * INNER * INNER);

  // step 0 pre: proj0 GEMM + cvt head_w[0] -> hb0
  proj_cvt<<<dim3(1024), dim3(256), 0, stream>>>(stateA, p0b, nsf, EMB_DIM,
      (const float4*)headw, (ushort4*)hb0, hn4);
  fuse_ln_gelu<<<dim3(TOKENS), dim3(256), 0, stream>>>(nsf,
      emb_w, inds, lnw, lnb, (ushort4*)stateI, 0, alpha);

  // mega 0: head0 (reads hb0) + proj1 (-> nsf) + cvt head_w[1] -> hb1
  mega<<<dim3(1024), dim3(512), 0, stream>>>(stateI, hb0, out,
      pwb, nsf,
      (const float4*)(headw + (size_t)1 * VOCAB * INNER), (ushort4*)hb1, hn4);
  fuse_ln_gelu<<<dim3(TOKENS), dim3(256), 0, stream>>>(nsf,
      emb_w + (size_t)1 * VOCAB * INNER, inds,
      lnw + INNER, lnb + INNER, (ushort4*)stateI, 1, alpha);

  // mega 1: head1 (reads hb1) + proj2 (-> nsf) + cvt head_w[2] -> hb0
  mega<<<dim3(1024), dim3(512), 0, stream>>>(stateI, hb1, out + (size_t)TOKENS * VOCAB,
      pwb + (size_t)INNER * INNER, nsf,
      (const float4*)(headw + (size_t)2 * VOCAB * INNER), (ushort4*)hb0, hn4);
  fuse_ln_gelu<<<dim3(TOKENS), dim3(256), 0, stream>>>(nsf,
      emb_w + (size_t)2 * VOCAB * INNER, inds,
      lnw + 2 * INNER, lnb + 2 * INNER, (ushort4*)stateI, 2, alpha);

  // mega 2: head2 only (reads hb0); grid = 500 so proj/cvt branches never run
  mega<<<dim3(500), dim3(512), 0, stream>>>(stateI, hb0, out + (size_t)2 * TOKENS * VOCAB,
      pwb, nsf, (const float4*)headw, (ushort4*)hb1, hn4);
}